// Round 7
// baseline (49.483 us; speedup 1.0000x reference)
//
#include <hip/hip_runtime.h>

#define BLOCK 256
#define SPAN  2048                // steps per block
#define ITERS 2                   // SPAN / (BLOCK*4)

// Affine transform x -> [[p,q],[r,s]] x + [u,v]
struct Xf { float p, q, r, s, u, v; };

__device__ __forceinline__ Xf xf_id() {
    Xf t; t.p = 1.f; t.q = 0.f; t.r = 0.f; t.s = 1.f; t.u = 0.f; t.v = 0.f;
    return t;
}

// result = L ∘ E  (E applied first, then L)
__device__ __forceinline__ Xf xf_compose(const Xf& E, const Xf& L) {
    Xf o;
    o.p = L.p * E.p + L.q * E.r;
    o.q = L.p * E.q + L.q * E.s;
    o.r = L.r * E.p + L.s * E.r;
    o.s = L.r * E.q + L.s * E.s;
    o.u = L.p * E.u + L.q * E.v + L.u;
    o.v = L.r * E.u + L.s * E.v + L.v;
    return o;
}

struct Par {
    float M11, M12, M21, Kx;
    float c0, c1;              // M22 = c0 + c1*rRia ; c1 = dt/C_in
    float cTo0, cIrr0, cQi0;
    float cIrr1, cQi1;
};

__device__ __forceinline__ Par make_par(
    const float* pRie, const float* pRea, const float* pCin, const float* pCen,
    const float* pAsi, const float* pAse, const float* pAii, const float* pAie)
{
    const float dt = 1800.0f;
    const float GA = 0.76f * 41.3f;
    float R_ie = *pRie, R_ea = *pRea, C_in = *pCin, C_en = *pCen;
    float asi = *pAsi, ase = *pAse, aii = *pAii, aie = *pAie;
    Par P;
    float iRie = 1.0f / R_ie;
    P.M11 = 1.0f + dt * (1.0f / R_ea + iRie) / C_en;
    P.M12 = -(dt * iRie) / C_en;
    P.M21 = -(dt * iRie) / C_in;
    P.Kx  = P.M12 * P.M21;
    P.c1  = dt / C_in;
    P.c0  = 1.0f + P.c1 * iRie;
    P.cTo0  = dt / (C_en * R_ea);
    P.cIrr0 = dt * ase * GA / C_en;
    P.cQi0  = dt * aie / C_en;
    P.cIrr1 = dt * asi * GA / C_in;
    P.cQi1  = dt * aii / C_in;
    return P;
}

// per-step transform; optionally export rR,b0,b1 for replay
__device__ __forceinline__ Xf step_xf(const Par& P, float to, float ir, float qi,
                                      float qa, float ra,
                                      float* rRo, float* b0o, float* b1o)
{
    float rR  = __builtin_amdgcn_rcpf(fmaxf(ra, 1e-6f));
    float b0  = P.cTo0 * to + P.cIrr0 * ir + P.cQi0 * qi;
    float b1  = P.c1 * fmaf(to, rR, qa) + P.cIrr1 * ir + P.cQi1 * qi;
    float M22 = fmaf(P.c1, rR, P.c0);
    float det = fmaf(P.M11, M22, -P.Kx);
    float rd  = __builtin_amdgcn_rcpf(det);
    Xf T;
    T.p =  M22 * rd;
    T.q = -P.M12 * rd;
    T.r = -P.M21 * rd;
    T.s =  P.M11 * rd;
    T.u = T.p * b0 + T.q * b1;
    T.v = T.r * b0 + T.s * b1;
    if (rRo) { *rRo = rR; *b0o = b0; *b1o = b1; }
    return T;
}

__device__ __forceinline__ Xf shfl_down_xf(const Xf& v, int d) {
    Xf o;
    o.p = __shfl_down(v.p, d, 64);
    o.q = __shfl_down(v.q, d, 64);
    o.r = __shfl_down(v.r, d, 64);
    o.s = __shfl_down(v.s, d, 64);
    o.u = __shfl_down(v.u, d, 64);
    o.v = __shfl_down(v.v, d, 64);
    return o;
}
__device__ __forceinline__ Xf shfl_up_xf(const Xf& v, int d) {
    Xf o;
    o.p = __shfl_up(v.p, d, 64);
    o.q = __shfl_up(v.q, d, 64);
    o.r = __shfl_up(v.r, d, 64);
    o.s = __shfl_up(v.s, d, 64);
    o.u = __shfl_up(v.u, d, 64);
    o.v = __shfl_up(v.v, d, 64);
    return o;
}

__device__ __forceinline__ void sm6_store(float* b, const Xf& v) {
    b[0] = v.p; b[1] = v.q; b[2] = v.r; b[3] = v.s; b[4] = v.u; b[5] = v.v;
}
__device__ __forceinline__ Xf sm6_load(const float* b) {
    Xf v; v.p = b[0]; v.q = b[1]; v.r = b[2]; v.s = b[3]; v.u = b[4]; v.v = b[5];
    return v;
}

// ---- guarded 5-array load of one 4-step sub-chunk ----
__device__ __forceinline__ void load4(
    const float* __restrict__ To, const float* __restrict__ Irr,
    const float* __restrict__ Qi, const float* __restrict__ Qa,
    const float* __restrict__ Ra, int gstep, int N,
    float* tox, float* irx, float* qix, float* qax, float* rax)
{
    if (gstep + 4 <= N) {
        float4 v;
        v = *(const float4*)(To  + gstep); tox[0]=v.x; tox[1]=v.y; tox[2]=v.z; tox[3]=v.w;
        v = *(const float4*)(Irr + gstep); irx[0]=v.x; irx[1]=v.y; irx[2]=v.z; irx[3]=v.w;
        v = *(const float4*)(Qi  + gstep); qix[0]=v.x; qix[1]=v.y; qix[2]=v.z; qix[3]=v.w;
        v = *(const float4*)(Qa  + gstep); qax[0]=v.x; qax[1]=v.y; qax[2]=v.z; qax[3]=v.w;
        v = *(const float4*)(Ra  + gstep); rax[0]=v.x; rax[1]=v.y; rax[2]=v.z; rax[3]=v.w;
    } else {
#pragma unroll
        for (int j = 0; j < 4; ++j) {
            int gi = gstep + j; bool val = gi < N;
            tox[j] = val ? To[gi]  : 0.f;
            irx[j] = val ? Irr[gi] : 0.f;
            qix[j] = val ? Qi[gi]  : 0.f;
            qax[j] = val ? Qa[gi]  : 0.f;
            rax[j] = val ? Ra[gi]  : 1.f;
        }
    }
}

// =============== k1: block aggregate via wave shuffle reduce ================
__global__ __launch_bounds__(BLOCK, 8) void k_blocksum(
    const float* __restrict__ To, const float* __restrict__ Irr,
    const float* __restrict__ Qi, const float* __restrict__ Qa,
    const float* __restrict__ Ra,
    const float* pRie, const float* pRea, const float* pCin, const float* pCen,
    const float* pAsi, const float* pAse, const float* pAii, const float* pAie,
    Xf* __restrict__ blkX, int N)
{
    __shared__ float smW[4 * 6];         // 4 wave totals
    const int t = threadIdx.x;
    const int lane = t & 63;
    const int w = t >> 6;
    const int blockBase = blockIdx.x * SPAN;
    Par P = make_par(pRie, pRea, pCin, pCen, pAsi, pAse, pAii, pAie);

    Xf blockAgg = xf_id();               // maintained by thread 0
#pragma unroll
    for (int iter = 0; iter < ITERS; ++iter) {
        const int gstep = blockBase + iter * 1024 + 4 * t;
        float tox[4], irx[4], qix[4], qax[4], rax[4];
        load4(To, Irr, Qi, Qa, Ra, gstep, N, tox, irx, qix, qax, rax);
        Xf v = xf_id();
#pragma unroll
        for (int j = 0; j < 4; ++j)
            if (gstep + j < N)
                v = xf_compose(v, step_xf(P, tox[j], irx[j], qix[j], qax[j], rax[j],
                                          nullptr, nullptr, nullptr));
        // ordered wave reduce: lane 0 ends with product of lanes [0,64) in order
#pragma unroll
        for (int d = 1; d < 64; d <<= 1) {
            Xf u = shfl_down_xf(v, d);   // later segment
            v = xf_compose(v, u);        // v earlier, u later
        }
        if (lane == 0) sm6_store(smW + w * 6, v);
        __syncthreads();
        if (t == 0) {
            Xf ia = sm6_load(smW + 0);
            ia = xf_compose(ia, sm6_load(smW + 6));
            ia = xf_compose(ia, sm6_load(smW + 12));
            ia = xf_compose(ia, sm6_load(smW + 18));
            blockAgg = xf_compose(blockAgg, ia);
        }
        __syncthreads();                 // protect smW before next iter writes
    }
    if (t == 0) blkX[blockIdx.x] = blockAgg;
}

// =============== k2: spine scan over block aggregates =======================
__device__ __forceinline__ void sm_store(float* sm, int i, const Xf& v) {
    float* b = sm + i * 7;
    b[0] = v.p; b[1] = v.q; b[2] = v.r; b[3] = v.s; b[4] = v.u; b[5] = v.v;
}
__device__ __forceinline__ Xf sm_load(const float* sm, int i) {
    const float* b = sm + i * 7;
    Xf v; v.p = b[0]; v.q = b[1]; v.r = b[2]; v.s = b[3]; v.u = b[4]; v.v = b[5];
    return v;
}
__device__ __forceinline__ Xf block_scan(Xf v, float* sm) {
    const int t = threadIdx.x;
    sm_store(sm, t, v);
    __syncthreads();
    for (int off = 1; off < BLOCK; off <<= 1) {
        Xf e;
        bool has = (t >= off);
        if (has) e = sm_load(sm, t - off);
        __syncthreads();
        if (has) { v = xf_compose(e, v); sm_store(sm, t, v); }
        __syncthreads();
    }
    return v;
}

__global__ __launch_bounds__(BLOCK) void k_mid(
    const Xf* __restrict__ blkX, float2* __restrict__ blkSt,
    const float* pTin0, int NB)
{
    const int t = threadIdx.x;
    const int ser = (NB + BLOCK - 1) / BLOCK;
    const int base = t * ser;
    Xf acc = xf_id();
    for (int j = 0; j < ser; ++j) {
        int i = base + j;
        if (i < NB) acc = xf_compose(acc, blkX[i]);
    }
    __shared__ float sm[BLOCK * 7];
    block_scan(acc, sm);
    Xf E = xf_id();
    if (t > 0) E = sm_load(sm, t - 1);
    float T0 = *pTin0;
    float x0 = (E.p + E.q) * T0 + E.u;
    float x1 = (E.r + E.s) * T0 + E.v;
    for (int j = 0; j < ser; ++j) {
        int i = base + j;
        if (i < NB) {
            blkSt[i] = make_float2(x0, x1);
            Xf T = blkX[i];
            float n0 = T.p * x0 + T.q * x1 + T.u;
            float n1 = T.r * x0 + T.s * x1 + T.v;
            x0 = n0; x1 = n1;
        }
    }
}

// =============== k3: emit Tin via wave shuffle scan =========================
__global__ __launch_bounds__(BLOCK, 4) void k_emit(
    const float* __restrict__ To, const float* __restrict__ Irr,
    const float* __restrict__ Qi, const float* __restrict__ Qa,
    const float* __restrict__ Ra,
    const float* pRie, const float* pRea, const float* pCin, const float* pCen,
    const float* pAsi, const float* pAse, const float* pAii, const float* pAie,
    const float2* __restrict__ blkSt, float* __restrict__ out, int N)
{
    __shared__ float smW[4 * ITERS * 6];   // wave totals per iter
    const int t = threadIdx.x;
    const int lane = t & 63;
    const int w = t >> 6;
    const int blockBase = blockIdx.x * SPAN;
    Par P = make_par(pRie, pRea, pCin, pCen, pAsi, pAse, pAii, pAie);

    float rRv[ITERS][4], b0v[ITERS][4], b1v[ITERS][4];
    Xf sc[ITERS];

    // phase A: load, build sub-chunk transforms, wave-inclusive scans
#pragma unroll
    for (int iter = 0; iter < ITERS; ++iter) {
        const int gstep = blockBase + iter * 1024 + 4 * t;
        float tox[4], irx[4], qix[4], qax[4], rax[4];
        load4(To, Irr, Qi, Qa, Ra, gstep, N, tox, irx, qix, qax, rax);
        Xf v = xf_id();
#pragma unroll
        for (int j = 0; j < 4; ++j) {
            Xf T = step_xf(P, tox[j], irx[j], qix[j], qax[j], rax[j],
                           &rRv[iter][j], &b0v[iter][j], &b1v[iter][j]);
            if (gstep + j < N) v = xf_compose(v, T);
        }
        // ordered wave inclusive scan
#pragma unroll
        for (int d = 1; d < 64; d <<= 1) {
            Xf u = shfl_up_xf(v, d);     // earlier segment
            if (lane >= d) v = xf_compose(u, v);
        }
        sc[iter] = v;
        if (lane == 63) sm6_store(smW + (w * ITERS + iter) * 6, v);
    }
    __syncthreads();

    // phase B: assemble exclusive prefixes, replay, store
    float2 B = blkSt[blockIdx.x];
    float Sx = B.x, Sy = B.y;            // state at current iter start
#pragma unroll
    for (int iter = 0; iter < ITERS; ++iter) {
        // earlier-wave prefix within this iter
        Xf Wpre = xf_id();
        for (int ww = 0; ww < w; ++ww)
            Wpre = xf_compose(Wpre, sm6_load(smW + (ww * ITERS + iter) * 6));
        // lane-exclusive from inclusive
        Xf lex = shfl_up_xf(sc[iter], 1);
        if (lane == 0) lex = xf_id();
        Xf E = xf_compose(Wpre, lex);    // Wpre first, then lex
        float x0 = E.p * Sx + E.q * Sy + E.u;
        float x1 = E.r * Sx + E.s * Sy + E.v;

        const int gstep = blockBase + iter * 1024 + 4 * t;
        float ov[4];
#pragma unroll
        for (int j = 0; j < 4; ++j) {
            float rR  = rRv[iter][j];
            float M22 = fmaf(P.c1, rR, P.c0);
            float det = fmaf(P.M11, M22, -P.Kx);
            float rd  = __builtin_amdgcn_rcpf(det);
            float r0 = x0 + b0v[iter][j];
            float r1 = x1 + b1v[iter][j];
            float n0 = (M22 * r0 - P.M12 * r1) * rd;
            float n1 = (P.M11 * r1 - P.M21 * r0) * rd;
            x0 = n0; x1 = n1; ov[j] = n1;
        }
        if (gstep + 4 <= N) {
            float4 o; o.x = ov[0]; o.y = ov[1]; o.z = ov[2]; o.w = ov[3];
            *(float4*)(out + gstep) = o;
        } else {
#pragma unroll
            for (int j = 0; j < 4; ++j) { int gi = gstep + j; if (gi < N) out[gi] = ov[j]; }
        }

        // advance iter-start state by full iter aggregate
        Xf A = sm6_load(smW + (0 * ITERS + iter) * 6);
        A = xf_compose(A, sm6_load(smW + (1 * ITERS + iter) * 6));
        A = xf_compose(A, sm6_load(smW + (2 * ITERS + iter) * 6));
        A = xf_compose(A, sm6_load(smW + (3 * ITERS + iter) * 6));
        float nSx = A.p * Sx + A.q * Sy + A.u;
        float nSy = A.r * Sx + A.s * Sy + A.v;
        Sx = nSx; Sy = nSy;
    }
}

// ============================  launcher  ====================================
extern "C" void kernel_launch(void* const* d_in, const int* in_sizes, int n_in,
                              void* d_out, int out_size, void* d_ws, size_t ws_size,
                              hipStream_t stream)
{
    (void)n_in; (void)out_size; (void)ws_size;
    const float* pRie = (const float*)d_in[0];
    const float* pRea = (const float*)d_in[1];
    const float* pCin = (const float*)d_in[2];
    const float* pCen = (const float*)d_in[3];
    const float* pAsi = (const float*)d_in[4];
    const float* pAse = (const float*)d_in[5];
    const float* pAii = (const float*)d_in[6];
    const float* pAie = (const float*)d_in[7];
    const float* pTin0 = (const float*)d_in[8];
    const float* To  = (const float*)d_in[9];
    const float* Irr = (const float*)d_in[10];
    const float* Qi  = (const float*)d_in[11];
    const float* Qa  = (const float*)d_in[12];
    const float* Ra  = (const float*)d_in[13];
    float* outp = (float*)d_out;
    int N = in_sizes[9];
    if (N <= 0) return;

    const int NB = (N + SPAN - 1) / SPAN;

    Xf* blkX = (Xf*)d_ws;
    size_t off = ((size_t)NB * sizeof(Xf) + 255) & ~(size_t)255;
    float2* blkSt = (float2*)((char*)d_ws + off);

    k_blocksum<<<NB, BLOCK, 0, stream>>>(To, Irr, Qi, Qa, Ra,
        pRie, pRea, pCin, pCen, pAsi, pAse, pAii, pAie, blkX, N);
    k_mid<<<1, BLOCK, 0, stream>>>(blkX, blkSt, pTin0, NB);
    k_emit<<<NB, BLOCK, 0, stream>>>(To, Irr, Qi, Qa, Ra,
        pRie, pRea, pCin, pCen, pAsi, pAse, pAii, pAie, blkSt, outp, N);
}

// Round 8
// 46.096 us; speedup vs baseline: 1.0735x; 1.0735x over previous
//
#include <hip/hip_runtime.h>

#define BLOCK 256
#define SPAN  2048                // steps per block
#define ITERS 2                   // SPAN / (BLOCK*4)

// Affine transform x -> [[p,q],[r,s]] x + [u,v]
struct Xf { float p, q, r, s, u, v; };

__device__ __forceinline__ Xf xf_id() {
    Xf t; t.p = 1.f; t.q = 0.f; t.r = 0.f; t.s = 1.f; t.u = 0.f; t.v = 0.f;
    return t;
}

// result = L ∘ E  (E applied first, then L)
__device__ __forceinline__ Xf xf_compose(const Xf& E, const Xf& L) {
    Xf o;
    o.p = L.p * E.p + L.q * E.r;
    o.q = L.p * E.q + L.q * E.s;
    o.r = L.r * E.p + L.s * E.r;
    o.s = L.r * E.q + L.s * E.s;
    o.u = L.p * E.u + L.q * E.v + L.u;
    o.v = L.r * E.u + L.s * E.v + L.v;
    return o;
}

struct Par {
    float M11, M12, M21, Kx;
    float c0, c1;              // M22 = c0 + c1*rRia ; c1 = dt/C_in
    float cTo0, cIrr0, cQi0;
    float cIrr1, cQi1;
};

__device__ __forceinline__ Par make_par(
    const float* pRie, const float* pRea, const float* pCin, const float* pCen,
    const float* pAsi, const float* pAse, const float* pAii, const float* pAie)
{
    const float dt = 1800.0f;
    const float GA = 0.76f * 41.3f;
    float R_ie = *pRie, R_ea = *pRea, C_in = *pCin, C_en = *pCen;
    float asi = *pAsi, ase = *pAse, aii = *pAii, aie = *pAie;
    Par P;
    float iRie = 1.0f / R_ie;
    P.M11 = 1.0f + dt * (1.0f / R_ea + iRie) / C_en;
    P.M12 = -(dt * iRie) / C_en;
    P.M21 = -(dt * iRie) / C_in;
    P.Kx  = P.M12 * P.M21;
    P.c1  = dt / C_in;
    P.c0  = 1.0f + P.c1 * iRie;
    P.cTo0  = dt / (C_en * R_ea);
    P.cIrr0 = dt * ase * GA / C_en;
    P.cQi0  = dt * aie / C_en;
    P.cIrr1 = dt * asi * GA / C_in;
    P.cQi1  = dt * aii / C_in;
    return P;
}

// per-step transform; optionally export rR,b0,b1 for replay
__device__ __forceinline__ Xf step_xf(const Par& P, float to, float ir, float qi,
                                      float qa, float ra,
                                      float* rRo, float* b0o, float* b1o)
{
    float rR  = __builtin_amdgcn_rcpf(fmaxf(ra, 1e-6f));
    float b0  = P.cTo0 * to + P.cIrr0 * ir + P.cQi0 * qi;
    float b1  = P.c1 * fmaf(to, rR, qa) + P.cIrr1 * ir + P.cQi1 * qi;
    float M22 = fmaf(P.c1, rR, P.c0);
    float det = fmaf(P.M11, M22, -P.Kx);
    float rd  = __builtin_amdgcn_rcpf(det);
    Xf T;
    T.p =  M22 * rd;
    T.q = -P.M12 * rd;
    T.r = -P.M21 * rd;
    T.s =  P.M11 * rd;
    T.u = T.p * b0 + T.q * b1;
    T.v = T.r * b0 + T.s * b1;
    if (rRo) { *rRo = rR; *b0o = b0; *b1o = b1; }
    return T;
}

__device__ __forceinline__ Xf shfl_down_xf(const Xf& v, int d) {
    Xf o;
    o.p = __shfl_down(v.p, d, 64);
    o.q = __shfl_down(v.q, d, 64);
    o.r = __shfl_down(v.r, d, 64);
    o.s = __shfl_down(v.s, d, 64);
    o.u = __shfl_down(v.u, d, 64);
    o.v = __shfl_down(v.v, d, 64);
    return o;
}
__device__ __forceinline__ Xf shfl_up_xf(const Xf& v, int d) {
    Xf o;
    o.p = __shfl_up(v.p, d, 64);
    o.q = __shfl_up(v.q, d, 64);
    o.r = __shfl_up(v.r, d, 64);
    o.s = __shfl_up(v.s, d, 64);
    o.u = __shfl_up(v.u, d, 64);
    o.v = __shfl_up(v.v, d, 64);
    return o;
}

__device__ __forceinline__ void sm6_store(float* b, const Xf& v) {
    b[0] = v.p; b[1] = v.q; b[2] = v.r; b[3] = v.s; b[4] = v.u; b[5] = v.v;
}
__device__ __forceinline__ Xf sm6_load(const float* b) {
    Xf v; v.p = b[0]; v.q = b[1]; v.r = b[2]; v.s = b[3]; v.u = b[4]; v.v = b[5];
    return v;
}

// ---- guarded 5-array load of one 4-step sub-chunk ----
__device__ __forceinline__ void load4(
    const float* __restrict__ To, const float* __restrict__ Irr,
    const float* __restrict__ Qi, const float* __restrict__ Qa,
    const float* __restrict__ Ra, int gstep, int N,
    float* tox, float* irx, float* qix, float* qax, float* rax)
{
    if (gstep + 4 <= N) {
        float4 v;
        v = *(const float4*)(To  + gstep); tox[0]=v.x; tox[1]=v.y; tox[2]=v.z; tox[3]=v.w;
        v = *(const float4*)(Irr + gstep); irx[0]=v.x; irx[1]=v.y; irx[2]=v.z; irx[3]=v.w;
        v = *(const float4*)(Qi  + gstep); qix[0]=v.x; qix[1]=v.y; qix[2]=v.z; qix[3]=v.w;
        v = *(const float4*)(Qa  + gstep); qax[0]=v.x; qax[1]=v.y; qax[2]=v.z; qax[3]=v.w;
        v = *(const float4*)(Ra  + gstep); rax[0]=v.x; rax[1]=v.y; rax[2]=v.z; rax[3]=v.w;
    } else {
#pragma unroll
        for (int j = 0; j < 4; ++j) {
            int gi = gstep + j; bool val = gi < N;
            tox[j] = val ? To[gi]  : 0.f;
            irx[j] = val ? Irr[gi] : 0.f;
            qix[j] = val ? Qi[gi]  : 0.f;
            qax[j] = val ? Qa[gi]  : 0.f;
            rax[j] = val ? Ra[gi]  : 1.f;
        }
    }
}

// =============== k1: block aggregate via wave shuffle reduce ================
__global__ __launch_bounds__(BLOCK, 8) void k_blocksum(
    const float* __restrict__ To, const float* __restrict__ Irr,
    const float* __restrict__ Qi, const float* __restrict__ Qa,
    const float* __restrict__ Ra,
    const float* pRie, const float* pRea, const float* pCin, const float* pCen,
    const float* pAsi, const float* pAse, const float* pAii, const float* pAie,
    Xf* __restrict__ blkX, int N)
{
    __shared__ float smW[4 * ITERS * 6];   // wave totals per iter
    const int t = threadIdx.x;
    const int lane = t & 63;
    const int w = t >> 6;
    const int blockBase = blockIdx.x * SPAN;
    Par P = make_par(pRie, pRea, pCin, pCen, pAsi, pAse, pAii, pAie);

#pragma unroll
    for (int iter = 0; iter < ITERS; ++iter) {
        const int gstep = blockBase + iter * 1024 + 4 * t;
        float tox[4], irx[4], qix[4], qax[4], rax[4];
        load4(To, Irr, Qi, Qa, Ra, gstep, N, tox, irx, qix, qax, rax);
        Xf v = xf_id();
#pragma unroll
        for (int j = 0; j < 4; ++j)
            if (gstep + j < N)
                v = xf_compose(v, step_xf(P, tox[j], irx[j], qix[j], qax[j], rax[j],
                                          nullptr, nullptr, nullptr));
        // ordered wave reduce: lane 0 ends with product of lanes [0,64) in order
#pragma unroll
        for (int d = 1; d < 64; d <<= 1) {
            Xf u = shfl_down_xf(v, d);   // later segment
            v = xf_compose(v, u);        // v earlier, u later
        }
        if (lane == 0) sm6_store(smW + (w * ITERS + iter) * 6, v);
    }
    __syncthreads();
    if (t == 0) {
        Xf acc = xf_id();
#pragma unroll
        for (int iter = 0; iter < ITERS; ++iter)
            for (int ww = 0; ww < 4; ++ww)
                acc = xf_compose(acc, sm6_load(smW + (ww * ITERS + iter) * 6));
        blkX[blockIdx.x] = acc;
    }
}

// =============== k2: per-block spine reduce + emit ==========================
__global__ __launch_bounds__(BLOCK, 4) void k_emit(
    const float* __restrict__ To, const float* __restrict__ Irr,
    const float* __restrict__ Qi, const float* __restrict__ Qa,
    const float* __restrict__ Ra,
    const float* pRie, const float* pRea, const float* pCin, const float* pCen,
    const float* pAsi, const float* pAse, const float* pAii, const float* pAie,
    const float* pTin0, const Xf* __restrict__ blkX,
    float* __restrict__ out, int N, int NB)
{
    __shared__ float smW[4 * ITERS * 6];   // wave totals per iter (intra-block scan)
    __shared__ float smSp[4 * 6];          // spine wave partials
    __shared__ float smE[2];               // block start state
    const int t = threadIdx.x;
    const int lane = t & 63;
    const int w = t >> 6;
    const int b = blockIdx.x;
    const int blockBase = b * SPAN;
    Par P = make_par(pRie, pRea, pCin, pCen, pAsi, pAse, pAii, pAie);

    float rRv[ITERS][4], b0v[ITERS][4], b1v[ITERS][4];
    Xf sc[ITERS];

    // phase A: load inputs, per-step transforms, wave-inclusive scans
#pragma unroll
    for (int iter = 0; iter < ITERS; ++iter) {
        const int gstep = blockBase + iter * 1024 + 4 * t;
        float tox[4], irx[4], qix[4], qax[4], rax[4];
        load4(To, Irr, Qi, Qa, Ra, gstep, N, tox, irx, qix, qax, rax);
        Xf v = xf_id();
#pragma unroll
        for (int j = 0; j < 4; ++j) {
            Xf T = step_xf(P, tox[j], irx[j], qix[j], qax[j], rax[j],
                           &rRv[iter][j], &b0v[iter][j], &b1v[iter][j]);
            if (gstep + j < N) v = xf_compose(v, T);
        }
        // ordered wave inclusive scan
#pragma unroll
        for (int d = 1; d < 64; d <<= 1) {
            Xf u = shfl_up_xf(v, d);     // earlier segment
            if (lane >= d) v = xf_compose(u, v);
        }
        sc[iter] = v;
        if (lane == 63) sm6_store(smW + (w * ITERS + iter) * 6, v);
    }

    // spine: ordered reduce of blkX[0..b) -> block start state (overlaps phase A)
    {
        const int SER = (NB + BLOCK - 1) / BLOCK;
        Xf acc = xf_id();
        for (int j = 0; j < SER; ++j) {
            int idx = t * SER + j;
            if (idx < b) acc = xf_compose(acc, blkX[idx]);
        }
#pragma unroll
        for (int d = 1; d < 64; d <<= 1) {
            Xf u = shfl_down_xf(acc, d);
            acc = xf_compose(acc, u);
        }
        if (lane == 0) sm6_store(smSp + w * 6, acc);
    }
    __syncthreads();   // covers smW and smSp
    if (t == 0) {
        Xf A = sm6_load(smSp + 0);
        A = xf_compose(A, sm6_load(smSp + 6));
        A = xf_compose(A, sm6_load(smSp + 12));
        A = xf_compose(A, sm6_load(smSp + 18));
        float T0 = *pTin0;
        smE[0] = (A.p + A.q) * T0 + A.u;
        smE[1] = (A.r + A.s) * T0 + A.v;
    }
    __syncthreads();

    // phase B: assemble exclusive prefixes, replay, store
    float Sx = smE[0], Sy = smE[1];      // state at current iter start
#pragma unroll
    for (int iter = 0; iter < ITERS; ++iter) {
        // earlier-wave prefix within this iter
        Xf Wpre = xf_id();
        for (int ww = 0; ww < w; ++ww)
            Wpre = xf_compose(Wpre, sm6_load(smW + (ww * ITERS + iter) * 6));
        // lane-exclusive from inclusive
        Xf lex = shfl_up_xf(sc[iter], 1);
        if (lane == 0) lex = xf_id();
        Xf E = xf_compose(Wpre, lex);    // Wpre first, then lex
        float x0 = E.p * Sx + E.q * Sy + E.u;
        float x1 = E.r * Sx + E.s * Sy + E.v;

        const int gstep = blockBase + iter * 1024 + 4 * t;
        float ov[4];
#pragma unroll
        for (int j = 0; j < 4; ++j) {
            float rR  = rRv[iter][j];
            float M22 = fmaf(P.c1, rR, P.c0);
            float det = fmaf(P.M11, M22, -P.Kx);
            float rd  = __builtin_amdgcn_rcpf(det);
            float r0 = x0 + b0v[iter][j];
            float r1 = x1 + b1v[iter][j];
            float n0 = (M22 * r0 - P.M12 * r1) * rd;
            float n1 = (P.M11 * r1 - P.M21 * r0) * rd;
            x0 = n0; x1 = n1; ov[j] = n1;
        }
        if (gstep + 4 <= N) {
            float4 o; o.x = ov[0]; o.y = ov[1]; o.z = ov[2]; o.w = ov[3];
            *(float4*)(out + gstep) = o;
        } else {
#pragma unroll
            for (int j = 0; j < 4; ++j) { int gi = gstep + j; if (gi < N) out[gi] = ov[j]; }
        }

        // advance iter-start state by full iter aggregate
        Xf A = sm6_load(smW + (0 * ITERS + iter) * 6);
        A = xf_compose(A, sm6_load(smW + (1 * ITERS + iter) * 6));
        A = xf_compose(A, sm6_load(smW + (2 * ITERS + iter) * 6));
        A = xf_compose(A, sm6_load(smW + (3 * ITERS + iter) * 6));
        float nSx = A.p * Sx + A.q * Sy + A.u;
        float nSy = A.r * Sx + A.s * Sy + A.v;
        Sx = nSx; Sy = nSy;
    }
}

// ============================  launcher  ====================================
extern "C" void kernel_launch(void* const* d_in, const int* in_sizes, int n_in,
                              void* d_out, int out_size, void* d_ws, size_t ws_size,
                              hipStream_t stream)
{
    (void)n_in; (void)out_size; (void)ws_size;
    const float* pRie = (const float*)d_in[0];
    const float* pRea = (const float*)d_in[1];
    const float* pCin = (const float*)d_in[2];
    const float* pCen = (const float*)d_in[3];
    const float* pAsi = (const float*)d_in[4];
    const float* pAse = (const float*)d_in[5];
    const float* pAii = (const float*)d_in[6];
    const float* pAie = (const float*)d_in[7];
    const float* pTin0 = (const float*)d_in[8];
    const float* To  = (const float*)d_in[9];
    const float* Irr = (const float*)d_in[10];
    const float* Qi  = (const float*)d_in[11];
    const float* Qa  = (const float*)d_in[12];
    const float* Ra  = (const float*)d_in[13];
    float* outp = (float*)d_out;
    int N = in_sizes[9];
    if (N <= 0) return;

    const int NB = (N + SPAN - 1) / SPAN;
    Xf* blkX = (Xf*)d_ws;

    k_blocksum<<<NB, BLOCK, 0, stream>>>(To, Irr, Qi, Qa, Ra,
        pRie, pRea, pCin, pCen, pAsi, pAse, pAii, pAie, blkX, N);
    k_emit<<<NB, BLOCK, 0, stream>>>(To, Irr, Qi, Qa, Ra,
        pRie, pRea, pCin, pCen, pAsi, pAse, pAii, pAie, pTin0, blkX,
        outp, N, NB);
}